// Round 7
// baseline (678.760 us; speedup 1.0000x reference)
//
#include <hip/hip_runtime.h>

// GraphInteractionNetwork: B=8, P=512, D=16, E=64, H=128
// h(s,r) = relu(dist*w0 + G[s] + br[r]);  sum_s relu(x) = 0.5*(sum_s x + sum_s |x|)
//   sum_s x = w0*sum_s dist + sum_s G[s] + 128*br   (linear -> nearly free)
//   per-edge-component: add(g+br), fma(dist,w0,.), add-with-|.| modifier = 3 VALU ops
// agg[r] = hsum[r] @ We2 + 511*be2;  out = relu([agg,n] @ Wn1 + bn1) @ Wn2 + bn2
// R6: sender-split grid (2048 blocks, 4 quarters of 128 senders) for occupancy;
//     scalar f32 ops (v_pk gives no FP32 throughput on CDNA4 - 157.3 TF is scalar rate);
//     partials combined + node MLP in a third kernel (kernel-boundary coherence).

#define Bc 8
#define Pc 512
#define Dc 16
#define Ec 64
#define Hc 128
#define RT 8    // receivers per block
#define NB 16   // nodes per precompute block
#define SQ 4    // sender quarters
#define SL 128  // senders per edge block

// G[node][j], row-major
__global__ __launch_bounds__(256) void gin_precompute_G(
    const float* __restrict__ hIn, const float* __restrict__ We1, float* __restrict__ G) {
  __shared__ float sW[Dc][Hc];   // We1 rows 17..32 (ns block)
  __shared__ float sN[NB][Dc];
  const int tid = threadIdx.x;
  for (int i = tid; i < Dc * Hc; i += 256) sW[i >> 7][i & 127] = We1[17 * Hc + i];
  const int base = blockIdx.x * NB;
  for (int i = tid; i < NB * Dc; i += 256) sN[i >> 4][i & 15] = hIn[base * Dc + i];
  __syncthreads();
  for (int idx = tid; idx < NB * Hc; idx += 256) {
    int node = idx >> 7, j = idx & 127;
    float a = 0.f;
#pragma unroll
    for (int d = 0; d < Dc; ++d) a = fmaf(sN[node][d], sW[d][j], a);
    G[(size_t)(base + node) * Hc + j] = a;
  }
}

// grid: b*256 + rg*4 + q  (8 * 64 * 4 = 2048 blocks)
// partials[b][rg][q][k][j]  (fp32)
__global__ __launch_bounds__(256, 4) void gin_edges(
    const float* __restrict__ hIn, const float* __restrict__ We1, const float* __restrict__ be1,
    const float* __restrict__ G, float* __restrict__ partials) {
  const int tid  = threadIdx.x;
  const int j    = tid & 127;
  const int half = tid >> 7;     // sender 64-half within the 128-quarter
  const int blk  = blockIdx.x;
  const int q    = blk & 3;
  const int rg   = (blk >> 2) & 63;
  const int b    = blk >> 8;
  const int r0   = rg * RT;
  const int s0   = q * SL;

  const float* nodes = hIn + b * Pc * Dc;

  __shared__ float  s_nr[RT][Dc];      // 512 B
  __shared__ float4 s_dA[SL];          // dist k=0..3, 2 KB
  __shared__ float4 s_dB[SL];          // dist k=4..7, 2 KB
  __shared__ float  s_dsum[RT];        // 32 B
  __shared__ float  s_gsum[2][Hc];     // 1 KB
  __shared__ float  s_abs[2][RT][Hc];  // 8 KB

  if (tid < RT * Dc) s_nr[tid >> 4][tid & 15] = nodes[r0 * Dc + tid];
  if (tid < RT) s_dsum[tid] = 0.f;
  __syncthreads();

  // distances for this quarter's 128 senders: thread -> (sl = tid&127, kh = tid>>7)
  {
    const int sl = tid & 127, kh = tid >> 7;
    const float4* ns4 = (const float4*)(nodes + (s0 + sl) * Dc);
    float nsv[Dc];
    *(float4*)(nsv + 0)  = ns4[0];
    *(float4*)(nsv + 4)  = ns4[1];
    *(float4*)(nsv + 8)  = ns4[2];
    *(float4*)(nsv + 12) = ns4[3];
    float dk[4];
#pragma unroll
    for (int i = 0; i < 4; ++i) {
      const int k = kh * 4 + i;
      float a = 0.f;
#pragma unroll
      for (int d = 0; d < Dc; ++d) {
        float df = nsv[d] - s_nr[k][d];
        a = fmaf(df, df, a);
      }
      dk[i] = sqrtf(a);
    }
    float4 v = make_float4(dk[0], dk[1], dk[2], dk[3]);
    if (kh) s_dB[sl] = v; else s_dA[sl] = v;
#pragma unroll
    for (int i = 0; i < 4; ++i) atomicAdd(&s_dsum[kh * 4 + i], dk[i]);
  }

  // per-thread constants: w0, br[8] (scalar, all static indexing)
  const float w0 = We1[j];
  float br[RT];
  {
    const float be = be1[j];
#pragma unroll
    for (int k = 0; k < RT; ++k) br[k] = be;
#pragma unroll
    for (int d = 0; d < Dc; ++d) {
      const float wv = We1[(1 + d) * Hc + j];
#pragma unroll
      for (int k = 0; k < RT; ++k) br[k] = fmaf(s_nr[k][d], wv, br[k]);
    }
  }
  __syncthreads();  // dists + dsum ready

  // main: 64 senders for this half; 3 ops per (s,k): add, fma, add(|x|)
  float acc[RT];
#pragma unroll
  for (int k = 0; k < RT; ++k) acc[k] = 0.f;
  float gsum = 0.f;

  const float* gp = G + ((size_t)(b * Pc) + s0 + half * 64) * Hc + j;
  float gf0 = gp[0 * Hc], gf1 = gp[1 * Hc], gf2 = gp[2 * Hc], gf3 = gp[3 * Hc];

  for (int s5 = 0; s5 < 64; s5 += 4) {
    const float c0 = gf0, c1 = gf1, c2 = gf2, c3 = gf3;
    if (s5 < 60) {
      gf0 = gp[(s5 + 4) * Hc];
      gf1 = gp[(s5 + 5) * Hc];
      gf2 = gp[(s5 + 6) * Hc];
      gf3 = gp[(s5 + 7) * Hc];
    }
    const float cc[4] = {c0, c1, c2, c3};
#pragma unroll
    for (int i = 0; i < 4; ++i) {
      const int sl = half * 64 + s5 + i;
      const float4 dA = s_dA[sl];  // wave-uniform broadcast reads
      const float4 dB = s_dB[sl];
      const float g = cc[i];
      gsum += g;
      float x;
      x = fmaf(dA.x, w0, g + br[0]); acc[0] += fabsf(x);
      x = fmaf(dA.y, w0, g + br[1]); acc[1] += fabsf(x);
      x = fmaf(dA.z, w0, g + br[2]); acc[2] += fabsf(x);
      x = fmaf(dA.w, w0, g + br[3]); acc[3] += fabsf(x);
      x = fmaf(dB.x, w0, g + br[4]); acc[4] += fabsf(x);
      x = fmaf(dB.y, w0, g + br[5]); acc[5] += fabsf(x);
      x = fmaf(dB.z, w0, g + br[6]); acc[6] += fabsf(x);
      x = fmaf(dB.w, w0, g + br[7]); acc[7] += fabsf(x);
    }
  }

#pragma unroll
  for (int k = 0; k < RT; ++k) s_abs[half][k][j] = acc[k];
  s_gsum[half][j] = gsum;
  __syncthreads();

  // partial[k][j] = 0.5*(S_abs + S_lin), S_lin = dsum[k]*w0 + gsum_q + 128*br[k]
  {
    const float gq = s_gsum[0][j] + s_gsum[1][j];
    float* pout = partials + ((((size_t)b * 64 + rg) * SQ + q) * RT) * Hc;
#pragma unroll
    for (int kk = 0; kk < 4; ++kk) {
      const int k = half * 4 + kk;
      const float brk = half ? br[4 + kk] : br[kk];   // static indices, cndmask select
      const float Sabs = s_abs[0][k][j] + s_abs[1][k][j];
      const float Slin = fmaf(s_dsum[k], w0, fmaf(128.f, brk, gq));
      pout[(size_t)k * Hc + j] = 0.5f * (Sabs + Slin);
    }
  }
}

// grid: 512 blocks (b*64 + rg), 256 threads
__global__ __launch_bounds__(256) void gin_node(
    const float* __restrict__ hIn, const float* __restrict__ We1, const float* __restrict__ be1,
    const float* __restrict__ We2, const float* __restrict__ be2,
    const float* __restrict__ Wn1, const float* __restrict__ bn1,
    const float* __restrict__ Wn2, const float* __restrict__ bn2,
    const float* __restrict__ G, const float* __restrict__ partials, float* __restrict__ out) {
  const int tid  = threadIdx.x;
  const int j    = tid & 127;
  const int half = tid >> 7;
  const int bg   = blockIdx.x;
  const int b    = bg >> 6;
  const int rg   = bg & 63;
  const int r0   = rg * RT;

  const float* nodes = hIn + b * Pc * Dc;

  __shared__ float s_nr[RT][Dc];
  __shared__ float s_hsum[RT][Hc];
  __shared__ float s_nin[RT][Ec + Dc];
  __shared__ float s_h2[RT][Hc];

  if (tid < RT * Dc) s_nr[tid >> 4][tid & 15] = nodes[r0 * Dc + tid];
  __syncthreads();

  // br for this thread's 4 receivers (k = half*4 + kk)
  float br4[4];
#pragma unroll
  for (int kk = 0; kk < 4; ++kk) br4[kk] = be1[j];
#pragma unroll
  for (int d = 0; d < Dc; ++d) {
    const float wv = We1[(1 + d) * Hc + j];
#pragma unroll
    for (int kk = 0; kk < 4; ++kk) br4[kk] = fmaf(s_nr[half * 4 + kk][d], wv, br4[kk]);
  }

  // hsum = sum of 4 quarter-partials - relu(self-edge)
  {
    const float* pin = partials + ((size_t)bg * SQ * RT) * Hc;
#pragma unroll
    for (int kk = 0; kk < 4; ++kk) {
      const int k = half * 4 + kk;
      float p = pin[(0 * RT + k) * Hc + j] + pin[(1 * RT + k) * Hc + j] +
                pin[(2 * RT + k) * Hc + j] + pin[(3 * RT + k) * Hc + j];
      const float xs = G[((size_t)b * Pc + r0 + k) * Hc + j] + br4[kk];
      p -= fmaxf(xs, 0.f);
      s_hsum[k][j] = p;
    }
  }
  __syncthreads();

  // agg[k][e] = s_hsum[k] @ We2[:, e] + 511*be2[e]; 2 (k,e) per thread
  {
    const int e = tid & 63;
    const int kb = tid >> 6;  // 0..3
#pragma unroll
    for (int t2 = 0; t2 < 2; ++t2) {
      const int k = kb + t2 * 4;
      float a = 511.0f * be2[e];
#pragma unroll 16
      for (int jj = 0; jj < Hc; ++jj) a = fmaf(s_hsum[k][jj], We2[jj * Ec + e], a);
      s_nin[k][e] = a;
    }
  }
  if (tid < RT * Dc) s_nin[tid >> 4][Ec + (tid & 15)] = s_nr[tid >> 4][tid & 15];
  __syncthreads();

  // hidden: 4 receivers per thread
#pragma unroll
  for (int kk = 0; kk < 4; ++kk) {
    const int k = half * 4 + kk;
    float a = bn1[j];
#pragma unroll 16
    for (int i = 0; i < Ec + Dc; ++i) a = fmaf(s_nin[k][i], Wn1[i * Hc + j], a);
    s_h2[k][j] = fmaxf(a, 0.f);
  }
  __syncthreads();

  // output layer
  if (tid < RT * Dc) {
    const int k = tid >> 4, d = tid & 15;
    float a = bn2[d];
#pragma unroll 16
    for (int jj = 0; jj < Hc; ++jj) a = fmaf(s_h2[k][jj], Wn2[jj * Dc + d], a);
    out[b * Pc * Dc + (r0 + k) * Dc + d] = a;
  }
}

extern "C" void kernel_launch(void* const* d_in, const int* in_sizes, int n_in,
                              void* d_out, int out_size, void* d_ws, size_t ws_size,
                              hipStream_t stream) {
  const float* h   = (const float*)d_in[0];
  const float* We1 = (const float*)d_in[1];
  const float* be1 = (const float*)d_in[2];
  const float* We2 = (const float*)d_in[3];
  const float* be2 = (const float*)d_in[4];
  const float* Wn1 = (const float*)d_in[5];
  const float* bn1 = (const float*)d_in[6];
  const float* Wn2 = (const float*)d_in[7];
  const float* bn2 = (const float*)d_in[8];
  float* out = (float*)d_out;

  float* G        = (float*)d_ws;                        // 4096*128*4 = 2 MB
  float* partials = (float*)d_ws + (size_t)Bc * Pc * Hc; // 512*4*8*128*4 = 8 MB

  gin_precompute_G<<<(Bc * Pc) / NB, 256, 0, stream>>>(h, We1, G);
  gin_edges<<<Bc * 64 * SQ, 256, 0, stream>>>(h, We1, be1, G, partials);
  gin_node<<<Bc * 64, 256, 0, stream>>>(h, We1, be1, We2, be2, Wn1, bn1, Wn2, bn2, G, partials, out);
}

// Round 8
// 161.321 us; speedup vs baseline: 4.2075x; 4.2075x over previous
//
#include <hip/hip_runtime.h>

// GraphInteractionNetwork: B=8, P=512, D=16, E=64, H=128
// h(s,r) = relu(dist*w0 + G[s] + br[r]);  sum_s relu(x) = 0.5*(sum_s x + sum_s |x|)
//   sum_s x = w0*sum_s dist + sum_s G[s] + 128*br   (linear -> nearly free)
//   per-edge-component: add(g+br), fma(dist,w0,.), add-with-|.| modifier = 3 VALU ops
// agg[r] = hsum[r] @ We2 + 511*be2;  out = relu([agg,n] @ Wn1 + bn1) @ Wn2 + bn2
// R7 == R6 but NO second __launch_bounds__ arg: both (512,4) [R3] and (256,4) [R6]
//     made the compiler cap VGPRs at 64 and spill ~0.1-1.6 GB of scratch to HBM
//     (R6: FETCH 545MB/WRITE 1GB, VALUBusy 0.1-4%). Plain (256) gave clean allocs
//     in R0-R2. Occupancy comes from the 2048-block grid, not a hint.

#define Bc 8
#define Pc 512
#define Dc 16
#define Ec 64
#define Hc 128
#define RT 8    // receivers per block
#define NB 16   // nodes per precompute block
#define SQ 4    // sender quarters
#define SL 128  // senders per edge block

// G[node][j], row-major
__global__ __launch_bounds__(256) void gin_precompute_G(
    const float* __restrict__ hIn, const float* __restrict__ We1, float* __restrict__ G) {
  __shared__ float sW[Dc][Hc];   // We1 rows 17..32 (ns block)
  __shared__ float sN[NB][Dc];
  const int tid = threadIdx.x;
  for (int i = tid; i < Dc * Hc; i += 256) sW[i >> 7][i & 127] = We1[17 * Hc + i];
  const int base = blockIdx.x * NB;
  for (int i = tid; i < NB * Dc; i += 256) sN[i >> 4][i & 15] = hIn[base * Dc + i];
  __syncthreads();
  for (int idx = tid; idx < NB * Hc; idx += 256) {
    int node = idx >> 7, j = idx & 127;
    float a = 0.f;
#pragma unroll
    for (int d = 0; d < Dc; ++d) a = fmaf(sN[node][d], sW[d][j], a);
    G[(size_t)(base + node) * Hc + j] = a;
  }
}

// grid: b*256 + rg*4 + q  (8 * 64 * 4 = 2048 blocks)
// partials[b][rg][q][k][j]  (fp32)
__global__ __launch_bounds__(256) void gin_edges(
    const float* __restrict__ hIn, const float* __restrict__ We1, const float* __restrict__ be1,
    const float* __restrict__ G, float* __restrict__ partials) {
  const int tid  = threadIdx.x;
  const int j    = tid & 127;
  const int half = tid >> 7;     // sender 64-half within the 128-quarter
  const int blk  = blockIdx.x;
  const int q    = blk & 3;
  const int rg   = (blk >> 2) & 63;
  const int b    = blk >> 8;
  const int r0   = rg * RT;
  const int s0   = q * SL;

  const float* nodes = hIn + b * Pc * Dc;

  __shared__ float  s_nr[RT][Dc];      // 512 B
  __shared__ float4 s_dA[SL];          // dist k=0..3, 2 KB
  __shared__ float4 s_dB[SL];          // dist k=4..7, 2 KB
  __shared__ float  s_dsum[RT];        // 32 B
  __shared__ float  s_gsum[2][Hc];     // 1 KB
  __shared__ float  s_abs[2][RT][Hc];  // 8 KB

  if (tid < RT * Dc) s_nr[tid >> 4][tid & 15] = nodes[r0 * Dc + tid];
  if (tid < RT) s_dsum[tid] = 0.f;
  __syncthreads();

  // distances for this quarter's 128 senders: thread -> (sl = tid&127, kh = tid>>7)
  {
    const int sl = tid & 127, kh = tid >> 7;
    const float4* ns4 = (const float4*)(nodes + (s0 + sl) * Dc);
    float nsv[Dc];
    *(float4*)(nsv + 0)  = ns4[0];
    *(float4*)(nsv + 4)  = ns4[1];
    *(float4*)(nsv + 8)  = ns4[2];
    *(float4*)(nsv + 12) = ns4[3];
    float dk[4];
#pragma unroll
    for (int i = 0; i < 4; ++i) {
      const int k = kh * 4 + i;
      float a = 0.f;
#pragma unroll
      for (int d = 0; d < Dc; ++d) {
        float df = nsv[d] - s_nr[k][d];
        a = fmaf(df, df, a);
      }
      dk[i] = sqrtf(a);
    }
    float4 v = make_float4(dk[0], dk[1], dk[2], dk[3]);
    if (kh) s_dB[sl] = v; else s_dA[sl] = v;
#pragma unroll
    for (int i = 0; i < 4; ++i) atomicAdd(&s_dsum[kh * 4 + i], dk[i]);
  }

  // per-thread constants: w0, br[8] (scalar, all static indexing)
  const float w0 = We1[j];
  float br[RT];
  {
    const float be = be1[j];
#pragma unroll
    for (int k = 0; k < RT; ++k) br[k] = be;
#pragma unroll
    for (int d = 0; d < Dc; ++d) {
      const float wv = We1[(1 + d) * Hc + j];
#pragma unroll
      for (int k = 0; k < RT; ++k) br[k] = fmaf(s_nr[k][d], wv, br[k]);
    }
  }
  __syncthreads();  // dists + dsum ready

  // main: 64 senders for this half; 3 ops per (s,k): add, fma, add(|x|)
  float acc[RT];
#pragma unroll
  for (int k = 0; k < RT; ++k) acc[k] = 0.f;
  float gsum = 0.f;

  const float* gp = G + ((size_t)(b * Pc) + s0 + half * 64) * Hc + j;
  float gf0 = gp[0 * Hc], gf1 = gp[1 * Hc], gf2 = gp[2 * Hc], gf3 = gp[3 * Hc];

  for (int s5 = 0; s5 < 64; s5 += 4) {
    const float c0 = gf0, c1 = gf1, c2 = gf2, c3 = gf3;
    if (s5 < 60) {
      gf0 = gp[(s5 + 4) * Hc];
      gf1 = gp[(s5 + 5) * Hc];
      gf2 = gp[(s5 + 6) * Hc];
      gf3 = gp[(s5 + 7) * Hc];
    }
    const float cc[4] = {c0, c1, c2, c3};
#pragma unroll
    for (int i = 0; i < 4; ++i) {
      const int sl = half * 64 + s5 + i;
      const float4 dA = s_dA[sl];  // wave-uniform broadcast reads
      const float4 dB = s_dB[sl];
      const float g = cc[i];
      gsum += g;
      float x;
      x = fmaf(dA.x, w0, g + br[0]); acc[0] += fabsf(x);
      x = fmaf(dA.y, w0, g + br[1]); acc[1] += fabsf(x);
      x = fmaf(dA.z, w0, g + br[2]); acc[2] += fabsf(x);
      x = fmaf(dA.w, w0, g + br[3]); acc[3] += fabsf(x);
      x = fmaf(dB.x, w0, g + br[4]); acc[4] += fabsf(x);
      x = fmaf(dB.y, w0, g + br[5]); acc[5] += fabsf(x);
      x = fmaf(dB.z, w0, g + br[6]); acc[6] += fabsf(x);
      x = fmaf(dB.w, w0, g + br[7]); acc[7] += fabsf(x);
    }
  }

#pragma unroll
  for (int k = 0; k < RT; ++k) s_abs[half][k][j] = acc[k];
  s_gsum[half][j] = gsum;
  __syncthreads();

  // partial[k][j] = 0.5*(S_abs + S_lin), S_lin = dsum[k]*w0 + gsum_q + 128*br[k]
  {
    const float gq = s_gsum[0][j] + s_gsum[1][j];
    float* pout = partials + ((((size_t)b * 64 + rg) * SQ + q) * RT) * Hc;
#pragma unroll
    for (int kk = 0; kk < 4; ++kk) {
      const int k = half * 4 + kk;
      const float brk = half ? br[4 + kk] : br[kk];   // static indices, cndmask select
      const float Sabs = s_abs[0][k][j] + s_abs[1][k][j];
      const float Slin = fmaf(s_dsum[k], w0, fmaf(128.f, brk, gq));
      pout[(size_t)k * Hc + j] = 0.5f * (Sabs + Slin);
    }
  }
}

// grid: 512 blocks (b*64 + rg), 256 threads
__global__ __launch_bounds__(256) void gin_node(
    const float* __restrict__ hIn, const float* __restrict__ We1, const float* __restrict__ be1,
    const float* __restrict__ We2, const float* __restrict__ be2,
    const float* __restrict__ Wn1, const float* __restrict__ bn1,
    const float* __restrict__ Wn2, const float* __restrict__ bn2,
    const float* __restrict__ G, const float* __restrict__ partials, float* __restrict__ out) {
  const int tid  = threadIdx.x;
  const int j    = tid & 127;
  const int half = tid >> 7;
  const int bg   = blockIdx.x;
  const int b    = bg >> 6;
  const int rg   = bg & 63;
  const int r0   = rg * RT;

  const float* nodes = hIn + b * Pc * Dc;

  __shared__ float s_nr[RT][Dc];
  __shared__ float s_hsum[RT][Hc];
  __shared__ float s_nin[RT][Ec + Dc];
  __shared__ float s_h2[RT][Hc];

  if (tid < RT * Dc) s_nr[tid >> 4][tid & 15] = nodes[r0 * Dc + tid];
  __syncthreads();

  // br for this thread's 4 receivers (k = half*4 + kk)
  float br4[4];
#pragma unroll
  for (int kk = 0; kk < 4; ++kk) br4[kk] = be1[j];
#pragma unroll
  for (int d = 0; d < Dc; ++d) {
    const float wv = We1[(1 + d) * Hc + j];
#pragma unroll
    for (int kk = 0; kk < 4; ++kk) br4[kk] = fmaf(s_nr[half * 4 + kk][d], wv, br4[kk]);
  }

  // hsum = sum of 4 quarter-partials - relu(self-edge)
  {
    const float* pin = partials + ((size_t)bg * SQ * RT) * Hc;
#pragma unroll
    for (int kk = 0; kk < 4; ++kk) {
      const int k = half * 4 + kk;
      float p = pin[(0 * RT + k) * Hc + j] + pin[(1 * RT + k) * Hc + j] +
                pin[(2 * RT + k) * Hc + j] + pin[(3 * RT + k) * Hc + j];
      const float xs = G[((size_t)b * Pc + r0 + k) * Hc + j] + br4[kk];
      p -= fmaxf(xs, 0.f);
      s_hsum[k][j] = p;
    }
  }
  __syncthreads();

  // agg[k][e] = s_hsum[k] @ We2[:, e] + 511*be2[e]; 2 (k,e) per thread
  {
    const int e = tid & 63;
    const int kb = tid >> 6;  // 0..3
#pragma unroll
    for (int t2 = 0; t2 < 2; ++t2) {
      const int k = kb + t2 * 4;
      float a = 511.0f * be2[e];
#pragma unroll 16
      for (int jj = 0; jj < Hc; ++jj) a = fmaf(s_hsum[k][jj], We2[jj * Ec + e], a);
      s_nin[k][e] = a;
    }
  }
  if (tid < RT * Dc) s_nin[tid >> 4][Ec + (tid & 15)] = s_nr[tid >> 4][tid & 15];
  __syncthreads();

  // hidden: 4 receivers per thread
#pragma unroll
  for (int kk = 0; kk < 4; ++kk) {
    const int k = half * 4 + kk;
    float a = bn1[j];
#pragma unroll 16
    for (int i = 0; i < Ec + Dc; ++i) a = fmaf(s_nin[k][i], Wn1[i * Hc + j], a);
    s_h2[k][j] = fmaxf(a, 0.f);
  }
  __syncthreads();

  // output layer
  if (tid < RT * Dc) {
    const int k = tid >> 4, d = tid & 15;
    float a = bn2[d];
#pragma unroll 16
    for (int jj = 0; jj < Hc; ++jj) a = fmaf(s_h2[k][jj], Wn2[jj * Dc + d], a);
    out[b * Pc * Dc + (r0 + k) * Dc + d] = a;
  }
}

extern "C" void kernel_launch(void* const* d_in, const int* in_sizes, int n_in,
                              void* d_out, int out_size, void* d_ws, size_t ws_size,
                              hipStream_t stream) {
  const float* h   = (const float*)d_in[0];
  const float* We1 = (const float*)d_in[1];
  const float* be1 = (const float*)d_in[2];
  const float* We2 = (const float*)d_in[3];
  const float* be2 = (const float*)d_in[4];
  const float* Wn1 = (const float*)d_in[5];
  const float* bn1 = (const float*)d_in[6];
  const float* Wn2 = (const float*)d_in[7];
  const float* bn2 = (const float*)d_in[8];
  float* out = (float*)d_out;

  float* G        = (float*)d_ws;                        // 4096*128*4 = 2 MB
  float* partials = (float*)d_ws + (size_t)Bc * Pc * Hc; // 512*4*8*128*4 = 8 MB

  gin_precompute_G<<<(Bc * Pc) / NB, 256, 0, stream>>>(h, We1, G);
  gin_edges<<<Bc * 64 * SQ, 256, 0, stream>>>(h, We1, be1, G, partials);
  gin_node<<<Bc * 64, 256, 0, stream>>>(h, We1, be1, We2, be2, Wn1, bn1, Wn2, bn2, G, partials, out);
}

// Round 9
// 123.247 us; speedup vs baseline: 5.5073x; 1.3089x over previous
//
#include <hip/hip_runtime.h>

// GraphInteractionNetwork: B=8, P=512, D=16, E=64, H=128
// h(s,r) = relu(dist*w0 + G[s] + br[r]);  sum_s relu(x) = 0.5*(sum_s x + sum_s |x|)
//   sum_s x = w0*sum_s dist + sum_s G[s] + 128*br per quarter (linear, cheap)
// agg[r] = hsum[r] @ We2 + 511*be2;  out = relu([agg,n] @ Wn1 + bn1) @ Wn2 + bn2
// R8 vs R7 (74us): (1) LDS atomicAdd dsum (64-lane same-addr serialization at
//     block start) -> __shfl_xor wave reduction; (2) G register-prefetch depth
//     4 -> 8 (ping-pong; ~2 compute-groups in flight covers L3 ~500cy latency);
//     (3) __launch_bounds__(256,2): empirical compiler rule caps VGPR at
//     256/min_waves -> 128 here = 4 waves/SIMD (args >=4 gave 64-VGPR spills).

#define Bc 8
#define Pc 512
#define Dc 16
#define Ec 64
#define Hc 128
#define RT 8    // receivers per block
#define NB 16   // nodes per precompute block
#define SQ 4    // sender quarters
#define SL 128  // senders per edge block

// G[node][j], row-major
__global__ __launch_bounds__(256) void gin_precompute_G(
    const float* __restrict__ hIn, const float* __restrict__ We1, float* __restrict__ G) {
  __shared__ float sW[Dc][Hc];   // We1 rows 17..32 (ns block)
  __shared__ float sN[NB][Dc];
  const int tid = threadIdx.x;
  for (int i = tid; i < Dc * Hc; i += 256) sW[i >> 7][i & 127] = We1[17 * Hc + i];
  const int base = blockIdx.x * NB;
  for (int i = tid; i < NB * Dc; i += 256) sN[i >> 4][i & 15] = hIn[base * Dc + i];
  __syncthreads();
  for (int idx = tid; idx < NB * Hc; idx += 256) {
    int node = idx >> 7, j = idx & 127;
    float a = 0.f;
#pragma unroll
    for (int d = 0; d < Dc; ++d) a = fmaf(sN[node][d], sW[d][j], a);
    G[(size_t)(base + node) * Hc + j] = a;
  }
}

// grid: b*256 + rg*4 + q  (2048 blocks); partials[b][rg][q][k][j]
__global__ __launch_bounds__(256, 2) void gin_edges(
    const float* __restrict__ hIn, const float* __restrict__ We1, const float* __restrict__ be1,
    const float* __restrict__ G, float* __restrict__ partials) {
  const int tid  = threadIdx.x;
  const int j    = tid & 127;
  const int half = tid >> 7;     // sender 64-half within the 128-quarter
  const int w    = tid >> 6;     // wave 0..3
  const int blk  = blockIdx.x;
  const int q    = blk & 3;
  const int rg   = (blk >> 2) & 63;
  const int b    = blk >> 8;
  const int r0   = rg * RT;
  const int s0   = q * SL;

  const float* nodes = hIn + b * Pc * Dc;

  __shared__ float  s_nr[RT][Dc];      // 512 B
  __shared__ float4 s_dA[SL];          // dist k=0..3, 2 KB
  __shared__ float4 s_dB[SL];          // dist k=4..7, 2 KB
  __shared__ float  s_dsum_w[4][4];    // per-wave dist sums, 64 B
  __shared__ float  s_gsum[2][Hc];     // 1 KB
  __shared__ float  s_abs[2][RT][Hc];  // 8 KB

  if (tid < RT * Dc) s_nr[tid >> 4][tid & 15] = nodes[r0 * Dc + tid];
  __syncthreads();

  // distances: thread -> (sl = tid&127, kh = tid>>7); lanes hold senders
  {
    const int sl = tid & 127, kh = tid >> 7;
    const float4* ns4 = (const float4*)(nodes + (s0 + sl) * Dc);
    float nsv[Dc];
    *(float4*)(nsv + 0)  = ns4[0];
    *(float4*)(nsv + 4)  = ns4[1];
    *(float4*)(nsv + 8)  = ns4[2];
    *(float4*)(nsv + 12) = ns4[3];
    float dk[4];
#pragma unroll
    for (int i = 0; i < 4; ++i) {
      const int k = kh * 4 + i;
      float a = 0.f;
#pragma unroll
      for (int d = 0; d < Dc; ++d) {
        float df = nsv[d] - s_nr[k][d];
        a = fmaf(df, df, a);
      }
      dk[i] = sqrtf(a);
    }
    float4 v = make_float4(dk[0], dk[1], dk[2], dk[3]);
    if (kh) s_dB[sl] = v; else s_dA[sl] = v;
    // wave shuffle-reduce dsum (NO atomics): lanes = 64 senders of this wave
    float r0s = dk[0], r1s = dk[1], r2s = dk[2], r3s = dk[3];
#pragma unroll
    for (int m = 1; m < 64; m <<= 1) {
      r0s += __shfl_xor(r0s, m);
      r1s += __shfl_xor(r1s, m);
      r2s += __shfl_xor(r2s, m);
      r3s += __shfl_xor(r3s, m);
    }
    if ((tid & 63) == 0) {
      s_dsum_w[w][0] = r0s; s_dsum_w[w][1] = r1s;
      s_dsum_w[w][2] = r2s; s_dsum_w[w][3] = r3s;
    }
  }

  // per-thread constants: w0, br[8]
  const float w0 = We1[j];
  float br[RT];
  {
    const float be = be1[j];
#pragma unroll
    for (int k = 0; k < RT; ++k) br[k] = be;
#pragma unroll
    for (int d = 0; d < Dc; ++d) {
      const float wv = We1[(1 + d) * Hc + j];
#pragma unroll
      for (int k = 0; k < RT; ++k) br[k] = fmaf(s_nr[k][d], wv, br[k]);
    }
  }
  __syncthreads();  // dists + dsum ready

  // main: 64 senders for this half, 16 groups of 4, depth-8 ping-pong prefetch
  float acc[RT];
#pragma unroll
  for (int k = 0; k < RT; ++k) acc[k] = 0.f;
  float gsum = 0.f;

  const float* gp = G + ((size_t)(b * Pc) + s0 + half * 64) * Hc + j;

  float gA[4], gB[4];
#pragma unroll
  for (int i = 0; i < 4; ++i) gA[i] = gp[(0 + i) * Hc];
#pragma unroll
  for (int i = 0; i < 4; ++i) gB[i] = gp[(4 + i) * Hc];

  auto compute = [&](int grp, const float (&c)[4]) {
#pragma unroll
    for (int i = 0; i < 4; ++i) {
      const int sl = half * 64 + grp * 4 + i;
      const float4 dA = s_dA[sl];  // broadcast reads
      const float4 dB = s_dB[sl];
      const float g = c[i];
      gsum += g;
      float x;
      x = fmaf(dA.x, w0, g + br[0]); acc[0] += fabsf(x);
      x = fmaf(dA.y, w0, g + br[1]); acc[1] += fabsf(x);
      x = fmaf(dA.z, w0, g + br[2]); acc[2] += fabsf(x);
      x = fmaf(dA.w, w0, g + br[3]); acc[3] += fabsf(x);
      x = fmaf(dB.x, w0, g + br[4]); acc[4] += fabsf(x);
      x = fmaf(dB.y, w0, g + br[5]); acc[5] += fabsf(x);
      x = fmaf(dB.z, w0, g + br[6]); acc[6] += fabsf(x);
      x = fmaf(dB.w, w0, g + br[7]); acc[7] += fabsf(x);
    }
  };

  for (int pr = 0; pr < 8; ++pr) {
    float cA[4] = {gA[0], gA[1], gA[2], gA[3]};
    if (pr < 7) {
#pragma unroll
      for (int i = 0; i < 4; ++i) gA[i] = gp[((2 * pr + 2) * 4 + i) * Hc];
    }
    compute(2 * pr, cA);
    float cB[4] = {gB[0], gB[1], gB[2], gB[3]};
    if (pr < 7) {
#pragma unroll
      for (int i = 0; i < 4; ++i) gB[i] = gp[((2 * pr + 3) * 4 + i) * Hc];
    }
    compute(2 * pr + 1, cB);
  }

#pragma unroll
  for (int k = 0; k < RT; ++k) s_abs[half][k][j] = acc[k];
  s_gsum[half][j] = gsum;
  __syncthreads();

  // partial[k][j] = 0.5*(S_abs + S_lin), S_lin = dsum[k]*w0 + gsum_q + 128*br[k]
  {
    const float gq = s_gsum[0][j] + s_gsum[1][j];
    float* pout = partials + ((((size_t)b * 64 + rg) * SQ + q) * RT) * Hc;
#pragma unroll
    for (int kk = 0; kk < 4; ++kk) {
      const int k = half * 4 + kk;
      const float brk = half ? br[4 + kk] : br[kk];   // static indices
      const float dsumk = s_dsum_w[half * 2][kk] + s_dsum_w[half * 2 + 1][kk];
      const float Sabs = s_abs[0][k][j] + s_abs[1][k][j];
      const float Slin = fmaf(dsumk, w0, fmaf(128.f, brk, gq));
      pout[(size_t)k * Hc + j] = 0.5f * (Sabs + Slin);
    }
  }
}

// grid: 512 blocks (b*64 + rg), 256 threads
__global__ __launch_bounds__(256) void gin_node(
    const float* __restrict__ hIn, const float* __restrict__ We1, const float* __restrict__ be1,
    const float* __restrict__ We2, const float* __restrict__ be2,
    const float* __restrict__ Wn1, const float* __restrict__ bn1,
    const float* __restrict__ Wn2, const float* __restrict__ bn2,
    const float* __restrict__ G, const float* __restrict__ partials, float* __restrict__ out) {
  const int tid  = threadIdx.x;
  const int j    = tid & 127;
  const int half = tid >> 7;
  const int bg   = blockIdx.x;
  const int b    = bg >> 6;
  const int rg   = bg & 63;
  const int r0   = rg * RT;

  const float* nodes = hIn + b * Pc * Dc;

  __shared__ float s_nr[RT][Dc];
  __shared__ float s_hsum[RT][Hc];
  __shared__ float s_nin[RT][Ec + Dc];
  __shared__ float s_h2[RT][Hc];

  if (tid < RT * Dc) s_nr[tid >> 4][tid & 15] = nodes[r0 * Dc + tid];
  __syncthreads();

  // br for this thread's 4 receivers (k = half*4 + kk)
  float br4[4];
#pragma unroll
  for (int kk = 0; kk < 4; ++kk) br4[kk] = be1[j];
#pragma unroll
  for (int d = 0; d < Dc; ++d) {
    const float wv = We1[(1 + d) * Hc + j];
#pragma unroll
    for (int kk = 0; kk < 4; ++kk) br4[kk] = fmaf(s_nr[half * 4 + kk][d], wv, br4[kk]);
  }

  // hsum = sum of 4 quarter-partials - relu(self-edge)
  {
    const float* pin = partials + ((size_t)bg * SQ * RT) * Hc;
#pragma unroll
    for (int kk = 0; kk < 4; ++kk) {
      const int k = half * 4 + kk;
      float p = pin[(0 * RT + k) * Hc + j] + pin[(1 * RT + k) * Hc + j] +
                pin[(2 * RT + k) * Hc + j] + pin[(3 * RT + k) * Hc + j];
      const float xs = G[((size_t)b * Pc + r0 + k) * Hc + j] + br4[kk];
      p -= fmaxf(xs, 0.f);
      s_hsum[k][j] = p;
    }
  }
  __syncthreads();

  // agg[k][e] = s_hsum[k] @ We2[:, e] + 511*be2[e]; 2 (k,e) per thread
  {
    const int e = tid & 63;
    const int kb = tid >> 6;  // 0..3
#pragma unroll
    for (int t2 = 0; t2 < 2; ++t2) {
      const int k = kb + t2 * 4;
      float a = 511.0f * be2[e];
#pragma unroll 16
      for (int jj = 0; jj < Hc; ++jj) a = fmaf(s_hsum[k][jj], We2[jj * Ec + e], a);
      s_nin[k][e] = a;
    }
  }
  if (tid < RT * Dc) s_nin[tid >> 4][Ec + (tid & 15)] = s_nr[tid >> 4][tid & 15];
  __syncthreads();

  // hidden: 4 receivers per thread
#pragma unroll
  for (int kk = 0; kk < 4; ++kk) {
    const int k = half * 4 + kk;
    float a = bn1[j];
#pragma unroll 16
    for (int i = 0; i < Ec + Dc; ++i) a = fmaf(s_nin[k][i], Wn1[i * Hc + j], a);
    s_h2[k][j] = fmaxf(a, 0.f);
  }
  __syncthreads();

  // output layer
  if (tid < RT * Dc) {
    const int k = tid >> 4, d = tid & 15;
    float a = bn2[d];
#pragma unroll 16
    for (int jj = 0; jj < Hc; ++jj) a = fmaf(s_h2[k][jj], Wn2[jj * Dc + d], a);
    out[b * Pc * Dc + (r0 + k) * Dc + d] = a;
  }
}

extern "C" void kernel_launch(void* const* d_in, const int* in_sizes, int n_in,
                              void* d_out, int out_size, void* d_ws, size_t ws_size,
                              hipStream_t stream) {
  const float* h   = (const float*)d_in[0];
  const float* We1 = (const float*)d_in[1];
  const float* be1 = (const float*)d_in[2];
  const float* We2 = (const float*)d_in[3];
  const float* be2 = (const float*)d_in[4];
  const float* Wn1 = (const float*)d_in[5];
  const float* bn1 = (const float*)d_in[6];
  const float* Wn2 = (const float*)d_in[7];
  const float* bn2 = (const float*)d_in[8];
  float* out = (float*)d_out;

  float* G        = (float*)d_ws;                        // 4096*128*4 = 2 MB
  float* partials = (float*)d_ws + (size_t)Bc * Pc * Hc; // 512*4*8*128*4 = 8 MB

  gin_precompute_G<<<(Bc * Pc) / NB, 256, 0, stream>>>(h, We1, G);
  gin_edges<<<Bc * 64 * SQ, 256, 0, stream>>>(h, We1, be1, G, partials);
  gin_node<<<Bc * 64, 256, 0, stream>>>(h, We1, be1, We2, be2, Wn1, bn1, Wn2, bn2, G, partials, out);
}